// Round 5
// baseline (328.543 us; speedup 1.0000x reference)
//
#include <hip/hip_runtime.h>
#include <stdint.h>

typedef float  f32x4  __attribute__((ext_vector_type(4)));
typedef short  bf16x8 __attribute__((ext_vector_type(8)));

static constexpr int Bb = 4, Ll = 2048, DM = 1024, DI = 2048;
static constexpr int M  = Bb * Ll;        // 8192 rows
static constexpr int K1 = DM;             // 1024
static constexpr int NPROJ = 256;         // 4 j-blocks * 64 (49 used)
static constexpr int CHUNK = 128, NCH = Ll / CHUNK;  // 16 chunks
static constexpr size_t GPS = (size_t)M * NPROJ;     // partial-G stride (elems)

__device__ __forceinline__ unsigned short f2bf(float f) {
  unsigned u = __float_as_uint(f);
  return (unsigned short)((u + 0x7FFFu + ((u >> 16) & 1u)) >> 16);
}

__device__ __forceinline__ void async16(const void* g, void* l) {
  __builtin_amdgcn_global_load_lds((__attribute__((address_space(1))) void*)g,
                                   (__attribute__((address_space(3))) void*)l,
                                   16, 0, 0);
}

// ---------------- K0: convert x->bf16, transpose W_in->bf16, build WbigT, bias ----
__global__ __launch_bounds__(256) void k0_prep(
    const float* __restrict__ x, const float* __restrict__ W_in,
    const float* __restrict__ conv_w, const float* __restrict__ conv_b,
    const float* __restrict__ W_delta, const float* __restrict__ b_delta,
    const float* __restrict__ W_B, const float* __restrict__ W_C,
    const float* __restrict__ Dv,
    unsigned short* __restrict__ x_bf,   // [M][K1]
    unsigned short* __restrict__ Wt,     // [2*DI][K1]  (W_in^T)
    unsigned short* __restrict__ WbigT,  // [NPROJ][DI]
    float* __restrict__ bias64)          // [64]
{
  const int t = threadIdx.x;
  const int bid = blockIdx.x;
  __shared__ float lds[64 * 65];

  if (bid < 4096) {                         // ---- x -> bf16 (8 elems/thread)
    size_t i0 = ((size_t)bid * 256 + t) * 8;
    float4 a = *(const float4*)(x + i0);
    float4 b = *(const float4*)(x + i0 + 4);
    union { unsigned short u[8]; bf16x8 v; } r;
    r.u[0] = f2bf(a.x); r.u[1] = f2bf(a.y); r.u[2] = f2bf(a.z); r.u[3] = f2bf(a.w);
    r.u[4] = f2bf(b.x); r.u[5] = f2bf(b.y); r.u[6] = f2bf(b.z); r.u[7] = f2bf(b.w);
    *(bf16x8*)(x_bf + i0) = r.v;
  } else if (bid < 4096 + 1024) {           // ---- W_in [1024][4096] -> Wt [4096][1024] bf16
    int q = bid - 4096;
    int tx = q & 63, ty = q >> 6;           // 64 n-tiles x 16 k-tiles
    int n0 = tx * 64, k0 = ty * 64;
    for (int i = t; i < 4096; i += 256) {
      int r = i >> 6, c = i & 63;
      lds[r * 65 + c] = W_in[(size_t)(k0 + r) * 4096 + n0 + c];
    }
    __syncthreads();
    for (int i = t; i < 1024; i += 256) {   // 4 cols per thread, ushort4 stores
      int n = i >> 4, k4 = (i & 15) * 4;
      union { unsigned short u[4]; uint2 v; } r;
      #pragma unroll
      for (int j = 0; j < 4; ++j) r.u[j] = f2bf(lds[(k4 + j) * 65 + n]);
      *(uint2*)(Wt + (size_t)(n0 + n) * 1024 + k0 + k4) = r.v;
    }
  } else if (bid < 4096 + 1024 + 2048) {    // ---- WbigT[j*64+n][c] = wsel(c,n)*conv_w[c][j]
    int q = bid - (4096 + 1024);
    int id = q * 256 + t;                   // 524288 items
    int row = id >> 11, c = id & 2047;
    int n = row & 63, jb = row >> 6;
    float v = 0.f;
    if (n < 16)      v = W_delta[c * 16 + n];
    else if (n < 32) v = W_B[c * 16 + (n - 16)];
    else if (n < 48) v = W_C[c * 16 + (n - 32)];
    else if (n == 48) v = Dv[c];
    v *= conv_w[c * 4 + jb];
    WbigT[(size_t)row * 2048 + c] = f2bf(v);
  } else {                                  // ---- bias64[n] = conv_b @ wsel(:,n) (+ b_delta)
    int n = bid - (4096 + 1024 + 2048);     // 0..63, one block each
    float s = 0.f;
    if (n < 49) {
      for (int c = t; c < 2048; c += 256) {
        float w;
        if (n < 16)      w = W_delta[c * 16 + n];
        else if (n < 32) w = W_B[c * 16 + (n - 16)];
        else if (n < 48) w = W_C[c * 16 + (n - 32)];
        else             w = Dv[c];
        s += conv_b[c] * w;
      }
    }
    #pragma unroll
    for (int m_ = 32; m_ >= 1; m_ >>= 1) s += __shfl_xor(s, m_);
    if ((t & 63) == 0) lds[t >> 6] = s;
    __syncthreads();
    if (t == 0) {
      float tot = lds[0] + lds[1] + lds[2] + lds[3];
      if (n < 16) tot += b_delta[n];
      if (n >= 49) tot = 0.f;
      bias64[n] = tot;
    }
  }
}

// ================= GEMM1: 128x64(out) 2-phase m97 structure, gated ===========
// B-tile = [gate rows n0..n0+63 | in rows 2048+n0..n0+63]; epilogue silu(g)*v.
// LDS swizzle: physical slot s = kc ^ ((row>>1)&3)  (2-way bank spread = free).
__global__ __launch_bounds__(256) void g1_gate(
    const unsigned short* __restrict__ A,   // x_bf [8192][1024]
    const unsigned short* __restrict__ Bt,  // Wt   [4096][1024]
    unsigned short* __restrict__ xg)        // [8192][2048]
{
  const int tid = threadIdx.x;
  const int lane = tid & 63, wid = tid >> 6;
  const int wm = wid >> 1, wn = wid & 1;
  const int lane15 = lane & 15, kg = lane >> 4;
  int f = blockIdx.x;                       // 2048 blocks
  int s = (f & 7) * 256 + (f >> 3);         // bijective XCD swizzle
  const int m0 = (s >> 5) * 128;
  const int n0 = (s & 31) * 64;

  constexpr int ACH = 512;                  // 128 rows * 4 chunks
  constexpr int TOT = ACH + 512;            // + 128 B-rows * 4
  __shared__ short sm[2][TOT * 8];

  f32x4 acc[4][4];
  #pragma unroll
  for (int a_ = 0; a_ < 4; ++a_)
    #pragma unroll
    for (int b_ = 0; b_ < 4; ++b_) acc[a_][b_] = f32x4{0.f, 0.f, 0.f, 0.f};

  auto stage = [&](int buf, int step) {
    const int kt = step << 5;
    #pragma unroll
    for (int i = 0; i < TOT / 256; ++i) {
      int q = i * 256 + tid;
      char* dst = (char*)(&sm[buf][0]) + q * 16;
      const unsigned short* src;
      if (q < ACH) {
        int row = q >> 2;
        int kc = (q & 3) ^ ((q >> 3) & 3);        // pre-swizzled source
        src = A + (size_t)(m0 + row) * K1 + kt + kc * 8;
      } else {
        int q2 = q - ACH;
        int row = q2 >> 2;
        int kc = (q2 & 3) ^ ((q2 >> 3) & 3);
        int grow = (row < 64) ? (n0 + row) : (2048 + n0 + (row - 64));
        src = Bt + (size_t)grow * K1 + kt + kc * 8;
      }
      async16(src, dst);
    }
  };

  stage(0, 0);
  __syncthreads();

  int buf = 0;
  for (int step = 0; step < 32; ++step) {
    if (step + 1 < 32) stage(buf ^ 1, step + 1);
    const char* smA = (const char*)(&sm[buf][0]);
    const char* smB = smA + ACH * 16;
    bf16x8 af[4], bfr[4];
    #pragma unroll
    for (int mf = 0; mf < 4; ++mf) {
      int row = wm * 64 + mf * 16 + lane15;
      int kc = kg ^ ((row >> 1) & 3);
      af[mf] = *(const bf16x8*)(smA + row * 64 + kc * 16);
    }
    #pragma unroll
    for (int ff = 0; ff < 4; ++ff) {
      int row = (ff >> 1) * 64 + wn * 32 + (ff & 1) * 16 + lane15;
      int kc = kg ^ ((row >> 1) & 3);
      bfr[ff] = *(const bf16x8*)(smB + row * 64 + kc * 16);
    }
    #pragma unroll
    for (int mf = 0; mf < 4; ++mf)
      #pragma unroll
      for (int ff = 0; ff < 4; ++ff)
        acc[mf][ff] = __builtin_amdgcn_mfma_f32_16x16x32_bf16(af[mf], bfr[ff], acc[mf][ff], 0, 0, 0);
    __syncthreads();
    buf ^= 1;
  }

  #pragma unroll
  for (int mf = 0; mf < 4; ++mf)
    #pragma unroll
    for (int ff = 0; ff < 2; ++ff) {
      int col = n0 + wn * 32 + ff * 16 + lane15;
      #pragma unroll
      for (int e = 0; e < 4; ++e) {
        int row = m0 + wm * 64 + mf * 16 + (lane >> 4) * 4 + e;
        float g = acc[mf][ff][e], v = acc[mf][ff + 2][e];
        float sg = g / (1.f + __expf(-g));
        xg[(size_t)row * 2048 + col] = f2bf(sg * v);
      }
    }
}

// ---------------- GEMM2: C_part[z] = xg * WbigT^T over K-half z --------------
__global__ __launch_bounds__(256) void gemm2_k(
    const unsigned short* __restrict__ A,
    const unsigned short* __restrict__ Bt,
    float* __restrict__ Gp)                  // 2 partials of [M][256]
{
  constexpr int BM = 64;
  const int tid = threadIdx.x;
  const int lane = tid & 63, wid = tid >> 6;
  const int wm = wid >> 1, wn = wid & 1;
  const int lane15 = lane & 15, kg = lane >> 4;
  const int m0 = blockIdx.y * BM;
  const int n0 = blockIdx.x * 128;
  const int koff = blockIdx.z * 1024;
  constexpr int ldK = 2048, NT = 32;

  constexpr int ACH = BM * 4;
  constexpr int TOT = ACH + 512;
  __shared__ short sm[2][TOT * 8];

  f32x4 acc[BM / 32][4];
  #pragma unroll
  for (int a_ = 0; a_ < BM / 32; ++a_)
    #pragma unroll
    for (int b_ = 0; b_ < 4; ++b_) acc[a_][b_] = f32x4{0.f, 0.f, 0.f, 0.f};

  auto stage = [&](int buf, int step) {
    const int kt = koff + (step << 5);
    #pragma unroll
    for (int i = 0; i < TOT / 256; ++i) {
      int q = i * 256 + tid;
      char* dst = (char*)(&sm[buf][0]) + q * 16;
      const unsigned short* src;
      if (q < ACH) {
        int row = q >> 2;
        int kc = (q & 3) ^ ((q >> 3) & 3);
        src = A + (size_t)(m0 + row) * ldK + kt + kc * 8;
      } else {
        int q2 = q - ACH;
        int row = q2 >> 2;
        int kc = (q2 & 3) ^ ((q2 >> 3) & 3);
        src = Bt + (size_t)(n0 + row) * ldK + kt + kc * 8;
      }
      async16(src, dst);
    }
  };

  stage(0, 0);
  __syncthreads();

  int buf = 0;
  for (int step = 0; step < NT; ++step) {
    if (step + 1 < NT) stage(buf ^ 1, step + 1);
    const char* smA = (const char*)(&sm[buf][0]);
    const char* smB = smA + ACH * 16;
    bf16x8 af[BM / 32], bfr[4];
    #pragma unroll
    for (int mf = 0; mf < BM / 32; ++mf) {
      int row = wm * (BM / 2) + mf * 16 + lane15;
      int kc = kg ^ ((row >> 1) & 3);
      af[mf] = *(const bf16x8*)(smA + row * 64 + kc * 16);
    }
    #pragma unroll
    for (int ff = 0; ff < 4; ++ff) {
      int row = wn * 64 + ff * 16 + lane15;
      int kc = kg ^ ((row >> 1) & 3);
      bfr[ff] = *(const bf16x8*)(smB + row * 64 + kc * 16);
    }
    #pragma unroll
    for (int mf = 0; mf < BM / 32; ++mf)
      #pragma unroll
      for (int ff = 0; ff < 4; ++ff)
        acc[mf][ff] = __builtin_amdgcn_mfma_f32_16x16x32_bf16(af[mf], bfr[ff], acc[mf][ff], 0, 0, 0);
    __syncthreads();
    buf ^= 1;
  }

  float* out = Gp + (size_t)blockIdx.z * GPS;
  #pragma unroll
  for (int mf = 0; mf < BM / 32; ++mf)
    #pragma unroll
    for (int ff = 0; ff < 4; ++ff) {
      int col = n0 + wn * 64 + ff * 16 + lane15;
      #pragma unroll
      for (int e = 0; e < 4; ++e) {
        int row = m0 + wm * (BM / 2) + mf * 16 + (lane >> 4) * 4 + e;
        out[(size_t)row * NPROJ + col] = acc[mf][ff][e];
      }
    }
}

// ---------------- K3: combine 4 j-blocks & 2 K-partials + chunk scan aggregates
__global__ __launch_bounds__(256) void k3_combine_scanA(
    const float* __restrict__ Gp, const float* __restrict__ bias64,
    float* __restrict__ a_arr, float* __restrict__ bd_arr,
    float* __restrict__ cm_arr, float* __restrict__ xcd_arr,
    float* __restrict__ aProd, float* __restrict__ hEnd)
{
  const int t = threadIdx.x;
  const int b = blockIdx.x >> 4, ch = blockIdx.x & 15;
  const int l0 = ch * CHUNK;
  __shared__ float comb[CHUNK][64];
  const size_t mbase = (size_t)b * 2048;

  for (int i = t; i < CHUNK * 64; i += 256) {
    int l = i >> 6, n = i & 63;
    float s = bias64[n];
    #pragma unroll
    for (int j = 0; j < 4; ++j) {
      int gl = l0 + l - 3 + j;
      if (gl >= 0) {
        size_t gi = (mbase + gl) * 256 + (j << 6) + n;
        s += Gp[gi] + Gp[gi + GPS];
      }
    }
    comb[l][n] = s;
  }
  __syncthreads();

  for (int i = t; i < CHUNK * 16; i += 256) {
    int l = i >> 4, n = i & 15;
    float d  = comb[l][n];
    float la = -0.5f * logf(1.0f + (float)(n + 1) * 0.0625f);
    float a  = __expf(d * la);
    float bd = d * comb[l][16 + n];
    size_t gi = ((mbase + l0 + l) << 4) + n;
    a_arr[gi] = a; bd_arr[gi] = bd; cm_arr[gi] = comb[l][32 + n];
    comb[l][n] = a; comb[l][16 + n] = bd;
  }
  if (t < CHUNK) xcd_arr[mbase + l0 + t] = comb[t][48];
  __syncthreads();

  if (t < 16) {
    float h = 0.f, p = 1.f;
    for (int l = 0; l < CHUNK; ++l) {
      float a = comb[l][t], bd = comb[l][16 + t];
      p *= a; h = a * h + bd;
    }
    int idx = ((b * 16 + ch) << 4) + t;
    aProd[idx] = p; hEnd[idx] = h;
  }
}

// ---------------- K456: per-chunk prefix + scan + y*w_out broadcast ----------
__global__ __launch_bounds__(256) void k456_scan_out(
    const float* __restrict__ a_arr, const float* __restrict__ bd_arr,
    const float* __restrict__ cm_arr, const float* __restrict__ xcd_arr,
    const float* __restrict__ aProd, const float* __restrict__ hEnd,
    const float* __restrict__ w_out, float* __restrict__ out)
{
  const int t = threadIdx.x;
  const int b = blockIdx.x >> 4, ch = blockIdx.x & 15;
  const size_t base = (size_t)b * 2048 + ch * CHUNK;
  __shared__ float ylds[CHUNK];

  if (t < 16) {
    const int n = t;
    float h = 0.f;
    for (int p = 0; p < ch; ++p) {           // local prefix over earlier chunks
      int idx = ((b * NCH + p) << 4) + n;
      h = aProd[idx] * h + hEnd[idx];
    }
    size_t gi = (base << 4) + n;
    float a0 = a_arr[gi], b0 = bd_arr[gi], c0 = cm_arr[gi];
    for (int l = 0; l < CHUNK; ++l) {
      float a1 = 0.f, b1 = 0.f, c1 = 0.f;
      if (l + 1 < CHUNK) {                   // 1-deep load pipeline
        size_t gin = gi + 16;
        a1 = a_arr[gin]; b1 = bd_arr[gin]; c1 = cm_arr[gin];
      }
      h = a0 * h + b0;
      float p = c0 * h;
      p += __shfl_xor(p, 1); p += __shfl_xor(p, 2);
      p += __shfl_xor(p, 4); p += __shfl_xor(p, 8);
      if (n == 0) ylds[l] = p + xcd_arr[base + l];
      a0 = a1; b0 = b1; c0 = c1; gi += 16;
    }
  }
  __syncthreads();

  float4 w4 = *(const float4*)(w_out + t * 4);
  for (int l = 0; l < CHUNK; ++l) {
    float yv = ylds[l];
    float4 o; o.x = yv * w4.x; o.y = yv * w4.y; o.z = yv * w4.z; o.w = yv * w4.w;
    *(float4*)(out + (base + l) * 1024 + t * 4) = o;
  }
}

extern "C" void kernel_launch(void* const* d_in, const int* in_sizes, int n_in,
                              void* d_out, int out_size, void* d_ws, size_t ws_size,
                              hipStream_t stream) {
  const float* x       = (const float*)d_in[0];
  const float* W_in    = (const float*)d_in[1];
  const float* conv_w  = (const float*)d_in[2];
  const float* conv_b  = (const float*)d_in[3];
  const float* W_delta = (const float*)d_in[4];
  const float* b_delta = (const float*)d_in[5];
  const float* W_B     = (const float*)d_in[6];
  const float* W_C     = (const float*)d_in[7];
  const float* Dv      = (const float*)d_in[8];
  const float* w_out   = (const float*)d_in[9];

  char* ws = (char*)d_ws;
  size_t off = 0;
  auto alloc = [&](size_t bytes) {
    size_t cur = off; off = (cur + bytes + 255) & ~(size_t)255; return ws + cur;
  };
  unsigned short* x_bf  = (unsigned short*)alloc((size_t)M * K1 * 2);      // 16.8MB
  unsigned short* Wt    = (unsigned short*)alloc((size_t)4096 * K1 * 2);   //  8.4MB
  unsigned short* WbigT = (unsigned short*)alloc((size_t)NPROJ * 2048 * 2);//  1.0MB
  float* bias64 = (float*)alloc(64 * 4);
  unsigned short* xg    = (unsigned short*)alloc((size_t)M * DI * 2);      // 33.6MB
  float* a_arr  = (float*)alloc((size_t)M * 16 * 4);
  float* bd_arr = (float*)alloc((size_t)M * 16 * 4);
  float* cm_arr = (float*)alloc((size_t)M * 16 * 4);
  float* xcd    = (float*)alloc((size_t)M * 4);
  float* aProd  = (float*)alloc(4 * NCH * 16 * 4);
  float* hEnd   = (float*)alloc(4 * NCH * 16 * 4);
  // Gp (2 x 8.4MB) aliases x_bf+Wt region: x_bf/Wt are dead after GEMM1.
  float* Gp = (float*)ws;

  k0_prep<<<7232, 256, 0, stream>>>(x, W_in, conv_w, conv_b, W_delta, b_delta,
                                    W_B, W_C, Dv, x_bf, Wt, WbigT, bias64);
  g1_gate<<<2048, 256, 0, stream>>>(x_bf, Wt, xg);
  gemm2_k<<<dim3(2, 128, 2), 256, 0, stream>>>(xg, WbigT, Gp);
  k3_combine_scanA<<<64, 256, 0, stream>>>(Gp, bias64, a_arr, bd_arr, cm_arr, xcd,
                                           aProd, hEnd);
  k456_scan_out<<<64, 256, 0, stream>>>(a_arr, bd_arr, cm_arr, xcd, aProd, hEnd,
                                        w_out, (float*)d_out);
}

// Round 6
// 259.946 us; speedup vs baseline: 1.2639x; 1.2639x over previous
//
#include <hip/hip_runtime.h>
#include <stdint.h>

typedef float  f32x4  __attribute__((ext_vector_type(4)));
typedef short  bf16x8 __attribute__((ext_vector_type(8)));

static constexpr int Bb = 4, Ll = 2048, DM = 1024, DI = 2048;
static constexpr int M  = Bb * Ll;        // 8192 rows
static constexpr int K1 = DM;             // 1024
static constexpr int NPROJ = 256;         // 4 j-blocks * 64 (49 used)
static constexpr int CHUNK = 32, NCH = Ll / CHUNK;   // 64 chunks -> 256 blocks
static constexpr size_t GPS = (size_t)M * NPROJ;     // partial-G stride (elems)

__device__ __forceinline__ unsigned short f2bf(float f) {
  unsigned u = __float_as_uint(f);
  return (unsigned short)((u + 0x7FFFu + ((u >> 16) & 1u)) >> 16);
}

__device__ __forceinline__ void async16(const void* g, void* l) {
  __builtin_amdgcn_global_load_lds((__attribute__((address_space(1))) void*)g,
                                   (__attribute__((address_space(3))) void*)l,
                                   16, 0, 0);
}

// ---------------- K0: convert x->bf16, transpose W_in->bf16, build WbigT, bias ----
__global__ __launch_bounds__(256) void k0_prep(
    const float* __restrict__ x, const float* __restrict__ W_in,
    const float* __restrict__ conv_w, const float* __restrict__ conv_b,
    const float* __restrict__ W_delta, const float* __restrict__ b_delta,
    const float* __restrict__ W_B, const float* __restrict__ W_C,
    const float* __restrict__ Dv,
    unsigned short* __restrict__ x_bf,   // [M][K1]
    unsigned short* __restrict__ Wt,     // [2*DI][K1]  (W_in^T)
    unsigned short* __restrict__ WbigT,  // [NPROJ][DI]
    float* __restrict__ bias64)          // [64]
{
  const int t = threadIdx.x;
  const int bid = blockIdx.x;
  __shared__ float lds[64 * 65];

  if (bid < 4096) {                         // ---- x -> bf16 (8 elems/thread)
    size_t i0 = ((size_t)bid * 256 + t) * 8;
    float4 a = *(const float4*)(x + i0);
    float4 b = *(const float4*)(x + i0 + 4);
    union { unsigned short u[8]; bf16x8 v; } r;
    r.u[0] = f2bf(a.x); r.u[1] = f2bf(a.y); r.u[2] = f2bf(a.z); r.u[3] = f2bf(a.w);
    r.u[4] = f2bf(b.x); r.u[5] = f2bf(b.y); r.u[6] = f2bf(b.z); r.u[7] = f2bf(b.w);
    *(bf16x8*)(x_bf + i0) = r.v;
  } else if (bid < 4096 + 1024) {           // ---- W_in [1024][4096] -> Wt [4096][1024] bf16
    int q = bid - 4096;
    int tx = q & 63, ty = q >> 6;           // 64 n-tiles x 16 k-tiles
    int n0 = tx * 64, k0 = ty * 64;
    for (int i = t; i < 4096; i += 256) {
      int r = i >> 6, c = i & 63;
      lds[r * 65 + c] = W_in[(size_t)(k0 + r) * 4096 + n0 + c];
    }
    __syncthreads();
    for (int i = t; i < 1024; i += 256) {   // 4 cols per thread, ushort4 stores
      int n = i >> 4, k4 = (i & 15) * 4;
      union { unsigned short u[4]; uint2 v; } r;
      #pragma unroll
      for (int j = 0; j < 4; ++j) r.u[j] = f2bf(lds[(k4 + j) * 65 + n]);
      *(uint2*)(Wt + (size_t)(n0 + n) * 1024 + k0 + k4) = r.v;
    }
  } else if (bid < 4096 + 1024 + 2048) {    // ---- WbigT[j*64+n][c] = wsel(c,n)*conv_w[c][j]
    int q = bid - (4096 + 1024);
    int id = q * 256 + t;                   // 524288 items
    int row = id >> 11, c = id & 2047;
    int n = row & 63, jb = row >> 6;
    float v = 0.f;
    if (n < 16)      v = W_delta[c * 16 + n];
    else if (n < 32) v = W_B[c * 16 + (n - 16)];
    else if (n < 48) v = W_C[c * 16 + (n - 32)];
    else if (n == 48) v = Dv[c];
    v *= conv_w[c * 4 + jb];
    WbigT[(size_t)row * 2048 + c] = f2bf(v);
  } else {                                  // ---- bias64[n] = conv_b @ wsel(:,n) (+ b_delta)
    int n = bid - (4096 + 1024 + 2048);     // 0..63, one block each
    float s = 0.f;
    if (n < 49) {
      for (int c = t; c < 2048; c += 256) {
        float w;
        if (n < 16)      w = W_delta[c * 16 + n];
        else if (n < 32) w = W_B[c * 16 + (n - 16)];
        else if (n < 48) w = W_C[c * 16 + (n - 32)];
        else             w = Dv[c];
        s += conv_b[c] * w;
      }
    }
    #pragma unroll
    for (int m_ = 32; m_ >= 1; m_ >>= 1) s += __shfl_xor(s, m_);
    if ((t & 63) == 0) lds[t >> 6] = s;
    __syncthreads();
    if (t == 0) {
      float tot = lds[0] + lds[1] + lds[2] + lds[3];
      if (n < 16) tot += b_delta[n];
      if (n >= 49) tot = 0.f;
      bias64[n] = tot;
    }
  }
}

// ================= GEMM1: 128x64(out) 2-phase m97 structure, gated ===========
// Natural grid dim3(32,64): x = n-tile (fast), y = m-tile. L2-friendly (R1: 78MB).
// LDS swizzle (verified conflict-free R5): read slot kg ^ ((row>>1)&3),
// source pre-swizzle (q&3)^((q>>3)&3).
__global__ __launch_bounds__(256) void g1_gate(
    const unsigned short* __restrict__ A,   // x_bf [8192][1024]
    const unsigned short* __restrict__ Bt,  // Wt   [4096][1024]
    unsigned short* __restrict__ xg)        // [8192][2048]
{
  const int tid = threadIdx.x;
  const int lane = tid & 63, wid = tid >> 6;
  const int wm = wid >> 1, wn = wid & 1;
  const int lane15 = lane & 15, kg = lane >> 4;
  const int m0 = blockIdx.y * 128;
  const int n0 = blockIdx.x * 64;

  constexpr int ACH = 512;                  // 128 rows * 4 chunks
  constexpr int TOT = ACH + 512;            // + 128 B-rows * 4
  __shared__ short sm[2][TOT * 8];

  f32x4 acc[4][4];
  #pragma unroll
  for (int a_ = 0; a_ < 4; ++a_)
    #pragma unroll
    for (int b_ = 0; b_ < 4; ++b_) acc[a_][b_] = f32x4{0.f, 0.f, 0.f, 0.f};

  auto stage = [&](int buf, int step) {
    const int kt = step << 5;
    #pragma unroll
    for (int i = 0; i < TOT / 256; ++i) {
      int q = i * 256 + tid;
      char* dst = (char*)(&sm[buf][0]) + q * 16;
      const unsigned short* src;
      if (q < ACH) {
        int row = q >> 2;
        int kc = (q & 3) ^ ((q >> 3) & 3);        // pre-swizzled source
        src = A + (size_t)(m0 + row) * K1 + kt + kc * 8;
      } else {
        int q2 = q - ACH;
        int row = q2 >> 2;
        int kc = (q2 & 3) ^ ((q2 >> 3) & 3);
        int grow = (row < 64) ? (n0 + row) : (2048 + n0 + (row - 64));
        src = Bt + (size_t)grow * K1 + kt + kc * 8;
      }
      async16(src, dst);
    }
  };

  stage(0, 0);
  __syncthreads();

  int buf = 0;
  for (int step = 0; step < 32; ++step) {
    if (step + 1 < 32) stage(buf ^ 1, step + 1);
    const char* smA = (const char*)(&sm[buf][0]);
    const char* smB = smA + ACH * 16;
    bf16x8 af[4], bfr[4];
    #pragma unroll
    for (int mf = 0; mf < 4; ++mf) {
      int row = wm * 64 + mf * 16 + lane15;
      int kc = kg ^ ((row >> 1) & 3);
      af[mf] = *(const bf16x8*)(smA + row * 64 + kc * 16);
    }
    #pragma unroll
    for (int ff = 0; ff < 4; ++ff) {
      int row = (ff >> 1) * 64 + wn * 32 + (ff & 1) * 16 + lane15;
      int kc = kg ^ ((row >> 1) & 3);
      bfr[ff] = *(const bf16x8*)(smB + row * 64 + kc * 16);
    }
    #pragma unroll
    for (int mf = 0; mf < 4; ++mf)
      #pragma unroll
      for (int ff = 0; ff < 4; ++ff)
        acc[mf][ff] = __builtin_amdgcn_mfma_f32_16x16x32_bf16(af[mf], bfr[ff], acc[mf][ff], 0, 0, 0);
    __syncthreads();
    buf ^= 1;
  }

  #pragma unroll
  for (int mf = 0; mf < 4; ++mf)
    #pragma unroll
    for (int ff = 0; ff < 2; ++ff) {
      int col = n0 + wn * 32 + ff * 16 + lane15;
      #pragma unroll
      for (int e = 0; e < 4; ++e) {
        int row = m0 + wm * 64 + mf * 16 + (lane >> 4) * 4 + e;
        float g = acc[mf][ff][e], v = acc[mf][ff + 2][e];
        float sg = g / (1.f + __expf(-g));
        xg[(size_t)row * 2048 + col] = f2bf(sg * v);
      }
    }
}

// ---------------- GEMM2: 128x128 tile, split-K z=2, partials ----------------
__global__ __launch_bounds__(256) void gemm2_k(
    const unsigned short* __restrict__ A,    // xg [8192][2048]
    const unsigned short* __restrict__ Bt,   // WbigT [256][2048]
    float* __restrict__ Gp)                  // 2 partials of [M][256]
{
  const int tid = threadIdx.x;
  const int lane = tid & 63, wid = tid >> 6;
  const int wm = wid >> 1, wn = wid & 1;
  const int lane15 = lane & 15, kg = lane >> 4;
  const int m0 = blockIdx.y * 128;
  const int n0 = blockIdx.x * 128;
  const int koff = blockIdx.z * 1024;
  constexpr int ldK = 2048, NT = 32;

  constexpr int ACH = 512;                  // 128 A-rows * 4
  constexpr int TOT = ACH + 512;            // + 128 B-rows * 4
  __shared__ short sm[2][TOT * 8];

  f32x4 acc[4][4];
  #pragma unroll
  for (int a_ = 0; a_ < 4; ++a_)
    #pragma unroll
    for (int b_ = 0; b_ < 4; ++b_) acc[a_][b_] = f32x4{0.f, 0.f, 0.f, 0.f};

  auto stage = [&](int buf, int step) {
    const int kt = koff + (step << 5);
    #pragma unroll
    for (int i = 0; i < TOT / 256; ++i) {
      int q = i * 256 + tid;
      char* dst = (char*)(&sm[buf][0]) + q * 16;
      const unsigned short* src;
      if (q < ACH) {
        int row = q >> 2;
        int kc = (q & 3) ^ ((q >> 3) & 3);
        src = A + (size_t)(m0 + row) * ldK + kt + kc * 8;
      } else {
        int q2 = q - ACH;
        int row = q2 >> 2;
        int kc = (q2 & 3) ^ ((q2 >> 3) & 3);
        src = Bt + (size_t)(n0 + row) * ldK + kt + kc * 8;
      }
      async16(src, dst);
    }
  };

  stage(0, 0);
  __syncthreads();

  int buf = 0;
  for (int step = 0; step < NT; ++step) {
    if (step + 1 < NT) stage(buf ^ 1, step + 1);
    const char* smA = (const char*)(&sm[buf][0]);
    const char* smB = smA + ACH * 16;
    bf16x8 af[4], bfr[4];
    #pragma unroll
    for (int mf = 0; mf < 4; ++mf) {
      int row = wm * 64 + mf * 16 + lane15;
      int kc = kg ^ ((row >> 1) & 3);
      af[mf] = *(const bf16x8*)(smA + row * 64 + kc * 16);
    }
    #pragma unroll
    for (int ff = 0; ff < 4; ++ff) {
      int row = wn * 64 + ff * 16 + lane15;
      int kc = kg ^ ((row >> 1) & 3);
      bfr[ff] = *(const bf16x8*)(smB + row * 64 + kc * 16);
    }
    #pragma unroll
    for (int mf = 0; mf < 4; ++mf)
      #pragma unroll
      for (int ff = 0; ff < 4; ++ff)
        acc[mf][ff] = __builtin_amdgcn_mfma_f32_16x16x32_bf16(af[mf], bfr[ff], acc[mf][ff], 0, 0, 0);
    __syncthreads();
    buf ^= 1;
  }

  float* out = Gp + (size_t)blockIdx.z * GPS;
  #pragma unroll
  for (int mf = 0; mf < 4; ++mf)
    #pragma unroll
    for (int ff = 0; ff < 4; ++ff) {
      int col = n0 + wn * 64 + ff * 16 + lane15;
      #pragma unroll
      for (int e = 0; e < 4; ++e) {
        int row = m0 + wm * 64 + mf * 16 + (lane >> 4) * 4 + e;
        out[(size_t)row * NPROJ + col] = acc[mf][ff][e];
      }
    }
}

// ---------------- K3: combine 4 j-blocks & 2 K-partials + chunk scan aggregates
// CHUNK=32 -> 256 blocks (1/CU)
__global__ __launch_bounds__(256) void k3_combine_scanA(
    const float* __restrict__ Gp, const float* __restrict__ bias64,
    float* __restrict__ a_arr, float* __restrict__ bd_arr,
    float* __restrict__ cm_arr, float* __restrict__ xcd_arr,
    float* __restrict__ aProd, float* __restrict__ hEnd)
{
  const int t = threadIdx.x;
  const int b = blockIdx.x >> 6, ch = blockIdx.x & 63;
  const int l0 = ch * CHUNK;
  __shared__ float comb[CHUNK][64];
  const size_t mbase = (size_t)b * 2048;

  for (int i = t; i < CHUNK * 64; i += 256) {
    int l = i >> 6, n = i & 63;
    float s = bias64[n];
    #pragma unroll
    for (int j = 0; j < 4; ++j) {
      int gl = l0 + l - 3 + j;
      if (gl >= 0) {
        size_t gi = (mbase + gl) * 256 + (j << 6) + n;
        s += Gp[gi] + Gp[gi + GPS];
      }
    }
    comb[l][n] = s;
  }
  __syncthreads();

  for (int i = t; i < CHUNK * 16; i += 256) {
    int l = i >> 4, n = i & 15;
    float d  = comb[l][n];
    float la = -0.5f * logf(1.0f + (float)(n + 1) * 0.0625f);
    float a  = __expf(d * la);
    float bd = d * comb[l][16 + n];
    size_t gi = ((mbase + l0 + l) << 4) + n;
    a_arr[gi] = a; bd_arr[gi] = bd; cm_arr[gi] = comb[l][32 + n];
    comb[l][n] = a; comb[l][16 + n] = bd;
  }
  if (t < CHUNK) xcd_arr[mbase + l0 + t] = comb[t][48];
  __syncthreads();

  if (t < 16) {
    float h = 0.f, p = 1.f;
    #pragma unroll 4
    for (int l = 0; l < CHUNK; ++l) {
      float a = comb[l][t], bd = comb[l][16 + t];
      p *= a; h = a * h + bd;
    }
    int idx = ((b * NCH + ch) << 4) + t;
    aProd[idx] = p; hEnd[idx] = h;
  }
}

// ---------------- K456: per-chunk prefix + scan + y*w_out broadcast ----------
// CHUNK=32 -> 256 blocks; write phase spreads 33.6MB over all CUs.
__global__ __launch_bounds__(256) void k456_scan_out(
    const float* __restrict__ a_arr, const float* __restrict__ bd_arr,
    const float* __restrict__ cm_arr, const float* __restrict__ xcd_arr,
    const float* __restrict__ aProd, const float* __restrict__ hEnd,
    const float* __restrict__ w_out, float* __restrict__ out)
{
  const int t = threadIdx.x;
  const int b = blockIdx.x >> 6, ch = blockIdx.x & 63;
  const size_t base = (size_t)b * 2048 + ch * CHUNK;
  __shared__ float ylds[CHUNK];

  if (t < 16) {
    const int n = t;
    float h = 0.f;
    for (int p = 0; p < ch; ++p) {           // prefix over earlier chunks (<=63)
      int idx = ((b * NCH + p) << 4) + n;
      h = aProd[idx] * h + hEnd[idx];
    }
    size_t gi = (base << 4) + n;
    float a0 = a_arr[gi], b0 = bd_arr[gi], c0 = cm_arr[gi];
    for (int l = 0; l < CHUNK; ++l) {
      float a1 = 0.f, b1 = 0.f, c1 = 0.f;
      if (l + 1 < CHUNK) {                   // 1-deep load pipeline
        size_t gin = gi + 16;
        a1 = a_arr[gin]; b1 = bd_arr[gin]; c1 = cm_arr[gin];
      }
      h = a0 * h + b0;
      float p = c0 * h;
      p += __shfl_xor(p, 1); p += __shfl_xor(p, 2);
      p += __shfl_xor(p, 4); p += __shfl_xor(p, 8);
      if (n == 0) ylds[l] = p + xcd_arr[base + l];
      a0 = a1; b0 = b1; c0 = c1; gi += 16;
    }
  }
  __syncthreads();

  float4 w4 = *(const float4*)(w_out + t * 4);
  #pragma unroll 4
  for (int l = 0; l < CHUNK; ++l) {
    float yv = ylds[l];
    float4 o; o.x = yv * w4.x; o.y = yv * w4.y; o.z = yv * w4.z; o.w = yv * w4.w;
    *(float4*)(out + (base + l) * 1024 + t * 4) = o;
  }
}

extern "C" void kernel_launch(void* const* d_in, const int* in_sizes, int n_in,
                              void* d_out, int out_size, void* d_ws, size_t ws_size,
                              hipStream_t stream) {
  const float* x       = (const float*)d_in[0];
  const float* W_in    = (const float*)d_in[1];
  const float* conv_w  = (const float*)d_in[2];
  const float* conv_b  = (const float*)d_in[3];
  const float* W_delta = (const float*)d_in[4];
  const float* b_delta = (const float*)d_in[5];
  const float* W_B     = (const float*)d_in[6];
  const float* W_C     = (const float*)d_in[7];
  const float* Dv      = (const float*)d_in[8];
  const float* w_out   = (const float*)d_in[9];

  char* ws = (char*)d_ws;
  size_t off = 0;
  auto alloc = [&](size_t bytes) {
    size_t cur = off; off = (cur + bytes + 255) & ~(size_t)255; return ws + cur;
  };
  unsigned short* x_bf  = (unsigned short*)alloc((size_t)M * K1 * 2);      // 16.8MB
  unsigned short* Wt    = (unsigned short*)alloc((size_t)4096 * K1 * 2);   //  8.4MB
  unsigned short* WbigT = (unsigned short*)alloc((size_t)NPROJ * 2048 * 2);//  1.0MB
  float* bias64 = (float*)alloc(64 * 4);
  unsigned short* xg    = (unsigned short*)alloc((size_t)M * DI * 2);      // 33.6MB
  float* a_arr  = (float*)alloc((size_t)M * 16 * 4);
  float* bd_arr = (float*)alloc((size_t)M * 16 * 4);
  float* cm_arr = (float*)alloc((size_t)M * 16 * 4);
  float* xcd    = (float*)alloc((size_t)M * 4);
  float* aProd  = (float*)alloc(4 * NCH * 16 * 4);
  float* hEnd   = (float*)alloc(4 * NCH * 16 * 4);
  // Gp (2 x 8.4MB) aliases x_bf+Wt region: x_bf/Wt are dead after GEMM1.
  float* Gp = (float*)ws;

  k0_prep<<<7232, 256, 0, stream>>>(x, W_in, conv_w, conv_b, W_delta, b_delta,
                                    W_B, W_C, Dv, x_bf, Wt, WbigT, bias64);
  g1_gate<<<dim3(32, 64), 256, 0, stream>>>(x_bf, Wt, xg);
  gemm2_k<<<dim3(2, 64, 2), 256, 0, stream>>>(xg, WbigT, Gp);
  k3_combine_scanA<<<256, 256, 0, stream>>>(Gp, bias64, a_arr, bd_arr, cm_arr, xcd,
                                            aProd, hEnd);
  k456_scan_out<<<256, 256, 0, stream>>>(a_arr, bd_arr, cm_arr, xcd, aProd, hEnd,
                                         w_out, (float*)d_out);
}

// Round 7
// 241.545 us; speedup vs baseline: 1.3602x; 1.0762x over previous
//
#include <hip/hip_runtime.h>
#include <stdint.h>

typedef float  f32x4  __attribute__((ext_vector_type(4)));
typedef short  bf16x8 __attribute__((ext_vector_type(8)));

static constexpr int Bb = 4, Ll = 2048, DM = 1024, DI = 2048;
static constexpr int M  = Bb * Ll;        // 8192 rows
static constexpr int K1 = DM;             // 1024
static constexpr int NPROJ = 256;         // 4 j-blocks * 64 (49 used)
static constexpr int CHUNK = 32, NCH = Ll / CHUNK;   // 64 chunks -> 256 blocks
static constexpr size_t GPS = (size_t)M * NPROJ;     // partial-G stride (elems)

__device__ __forceinline__ unsigned short f2bf(float f) {
  unsigned u = __float_as_uint(f);
  return (unsigned short)((u + 0x7FFFu + ((u >> 16) & 1u)) >> 16);
}

__device__ __forceinline__ void async16(const void* g, void* l) {
  __builtin_amdgcn_global_load_lds((__attribute__((address_space(1))) void*)g,
                                   (__attribute__((address_space(3))) void*)l,
                                   16, 0, 0);
}

// ---------------- K0: convert x->bf16, transpose W_in->bf16, build WbigT, bias ----
__global__ __launch_bounds__(256) void k0_prep(
    const float* __restrict__ x, const float* __restrict__ W_in,
    const float* __restrict__ conv_w, const float* __restrict__ conv_b,
    const float* __restrict__ W_delta, const float* __restrict__ b_delta,
    const float* __restrict__ W_B, const float* __restrict__ W_C,
    const float* __restrict__ Dv,
    unsigned short* __restrict__ x_bf,   // [M][K1]
    unsigned short* __restrict__ Wt,     // [2*DI][K1]  (W_in^T)
    unsigned short* __restrict__ WbigT,  // [NPROJ][DI]
    float* __restrict__ bias64)          // [64]
{
  const int t = threadIdx.x;
  const int bid = blockIdx.x;
  __shared__ float lds[64 * 65];

  if (bid < 4096) {                         // ---- x -> bf16 (8 elems/thread)
    size_t i0 = ((size_t)bid * 256 + t) * 8;
    float4 a = *(const float4*)(x + i0);
    float4 b = *(const float4*)(x + i0 + 4);
    union { unsigned short u[8]; bf16x8 v; } r;
    r.u[0] = f2bf(a.x); r.u[1] = f2bf(a.y); r.u[2] = f2bf(a.z); r.u[3] = f2bf(a.w);
    r.u[4] = f2bf(b.x); r.u[5] = f2bf(b.y); r.u[6] = f2bf(b.z); r.u[7] = f2bf(b.w);
    *(bf16x8*)(x_bf + i0) = r.v;
  } else if (bid < 4096 + 1024) {           // ---- W_in [1024][4096] -> Wt [4096][1024] bf16
    int q = bid - 4096;
    int tx = q & 63, ty = q >> 6;           // 64 n-tiles x 16 k-tiles
    int n0 = tx * 64, k0 = ty * 64;
    for (int i = t; i < 4096; i += 256) {
      int r = i >> 6, c = i & 63;
      lds[r * 65 + c] = W_in[(size_t)(k0 + r) * 4096 + n0 + c];
    }
    __syncthreads();
    for (int i = t; i < 1024; i += 256) {   // 4 cols per thread, ushort4 stores
      int n = i >> 4, k4 = (i & 15) * 4;
      union { unsigned short u[4]; uint2 v; } r;
      #pragma unroll
      for (int j = 0; j < 4; ++j) r.u[j] = f2bf(lds[(k4 + j) * 65 + n]);
      *(uint2*)(Wt + (size_t)(n0 + n) * 1024 + k0 + k4) = r.v;
    }
  } else if (bid < 4096 + 1024 + 2048) {    // ---- WbigT[j*64+n][c] = wsel(c,n)*conv_w[c][j]
    int q = bid - (4096 + 1024);
    int id = q * 256 + t;                   // 524288 items
    int row = id >> 11, c = id & 2047;
    int n = row & 63, jb = row >> 6;
    float v = 0.f;
    if (n < 16)      v = W_delta[c * 16 + n];
    else if (n < 32) v = W_B[c * 16 + (n - 16)];
    else if (n < 48) v = W_C[c * 16 + (n - 32)];
    else if (n == 48) v = Dv[c];
    v *= conv_w[c * 4 + jb];
    WbigT[(size_t)row * 2048 + c] = f2bf(v);
  } else {                                  // ---- bias64[n] = conv_b @ wsel(:,n) (+ b_delta)
    int n = bid - (4096 + 1024 + 2048);     // 0..63, one block each
    float s = 0.f;
    if (n < 49) {
      for (int c = t; c < 2048; c += 256) {
        float w;
        if (n < 16)      w = W_delta[c * 16 + n];
        else if (n < 32) w = W_B[c * 16 + (n - 16)];
        else if (n < 48) w = W_C[c * 16 + (n - 32)];
        else             w = Dv[c];
        s += conv_b[c] * w;
      }
    }
    #pragma unroll
    for (int m_ = 32; m_ >= 1; m_ >>= 1) s += __shfl_xor(s, m_);
    if ((t & 63) == 0) lds[t >> 6] = s;
    __syncthreads();
    if (t == 0) {
      float tot = lds[0] + lds[1] + lds[2] + lds[3];
      if (n < 16) tot += b_delta[n];
      if (n >= 49) tot = 0.f;
      bias64[n] = tot;
    }
  }
}

// ================= GEMM1: BK=64, 32 MFMA per drain, gated ====================
// Tile: 128 M-rows x 64 out-cols; B staged = 128 rows (64 gate | 64 in).
// LDS: 2 buf x 256 rows x 8 chunks x 16B = 64 KiB.
// Swizzle: physical slot = logical_slot ^ (row&7); per 16-lane group this puts
// 2 lanes/16B-slot (empirically free, same criterion as R5/R6-verified map).
__global__ __launch_bounds__(256) void g1_gate(
    const unsigned short* __restrict__ A,   // x_bf [8192][1024]
    const unsigned short* __restrict__ Bt,  // Wt   [4096][1024]
    unsigned short* __restrict__ xg)        // [8192][2048]
{
  const int tid = threadIdx.x;
  const int lane = tid & 63, wid = tid >> 6;
  const int wm = wid >> 1, wn = wid & 1;
  const int lane15 = lane & 15, kg = lane >> 4;
  const int m0 = blockIdx.y * 128;
  const int n0 = blockIdx.x * 64;

  constexpr int ACHUNK = 128 * 8;           // A: 128 rows * 8 chunks
  constexpr int TOT = 256 * 8;              // + B: 128 rows * 8 chunks
  __shared__ short sm[2][TOT * 8];

  f32x4 acc[4][4];
  #pragma unroll
  for (int a_ = 0; a_ < 4; ++a_)
    #pragma unroll
    for (int b_ = 0; b_ < 4; ++b_) acc[a_][b_] = f32x4{0.f, 0.f, 0.f, 0.f};

  auto stage = [&](int buf, int step) {
    const int kt = step << 6;               // 64 k-elems per tile
    #pragma unroll
    for (int i = 0; i < TOT / 256; ++i) {   // 8 loads/thread
      int p = i * 256 + tid;
      char* dst = (char*)(&sm[buf][0]) + p * 16;
      int row = p >> 3;
      int kcol = (p & 7) ^ (row & 7);       // inverse swizzle at source
      const unsigned short* src;
      if (row < 128) {
        src = A + (size_t)(m0 + row) * K1 + kt + kcol * 8;
      } else {
        int brow = row - 128;
        int grow = (brow < 64) ? (n0 + brow) : (2048 + n0 + (brow - 64));
        src = Bt + (size_t)grow * K1 + kt + kcol * 8;
      }
      async16(src, dst);
    }
  };

  stage(0, 0);
  __syncthreads();

  int buf = 0;
  for (int step = 0; step < 16; ++step) {
    if (step + 1 < 16) stage(buf ^ 1, step + 1);
    const char* smA = (const char*)(&sm[buf][0]);
    const char* smB = smA + ACHUNK * 16;
    bf16x8 af[4][2], bfr[4][2];
    #pragma unroll
    for (int mf = 0; mf < 4; ++mf) {
      int row = wm * 64 + mf * 16 + lane15;
      #pragma unroll
      for (int kk = 0; kk < 2; ++kk) {
        int slot = (kk * 4 + kg) ^ (row & 7);
        af[mf][kk] = *(const bf16x8*)(smA + (row * 8 + slot) * 16);
      }
    }
    #pragma unroll
    for (int ff = 0; ff < 4; ++ff) {
      int row = (ff >> 1) * 64 + wn * 32 + (ff & 1) * 16 + lane15;
      #pragma unroll
      for (int kk = 0; kk < 2; ++kk) {
        int slot = (kk * 4 + kg) ^ (row & 7);
        bfr[ff][kk] = *(const bf16x8*)(smB + (row * 8 + slot) * 16);
      }
    }
    #pragma unroll
    for (int kk = 0; kk < 2; ++kk)
      #pragma unroll
      for (int mf = 0; mf < 4; ++mf)
        #pragma unroll
        for (int ff = 0; ff < 4; ++ff)
          acc[mf][ff] = __builtin_amdgcn_mfma_f32_16x16x32_bf16(
              af[mf][kk], bfr[ff][kk], acc[mf][ff], 0, 0, 0);
    __syncthreads();
    buf ^= 1;
  }

  #pragma unroll
  for (int mf = 0; mf < 4; ++mf)
    #pragma unroll
    for (int ff = 0; ff < 2; ++ff) {
      int col = n0 + wn * 32 + ff * 16 + lane15;
      #pragma unroll
      for (int e = 0; e < 4; ++e) {
        int row = m0 + wm * 64 + mf * 16 + (lane >> 4) * 4 + e;
        float g = acc[mf][ff][e], v = acc[mf][ff + 2][e];
        float sg = g / (1.f + __expf(-g));
        xg[(size_t)row * 2048 + col] = f2bf(sg * v);
      }
    }
}

// ---------------- GEMM2: BK=64, BM=64 x BN=128, split-K z=2 ------------------
// LDS: 2 buf x (64+128) rows x 8 chunks x 16B = 48 KiB -> 3 blocks/CU.
__global__ __launch_bounds__(256) void gemm2_k(
    const unsigned short* __restrict__ A,    // xg [8192][2048]
    const unsigned short* __restrict__ Bt,   // WbigT [256][2048]
    float* __restrict__ Gp)                  // 2 partials of [M][256]
{
  const int tid = threadIdx.x;
  const int lane = tid & 63, wid = tid >> 6;
  const int wm = wid >> 1, wn = wid & 1;
  const int lane15 = lane & 15, kg = lane >> 4;
  const int m0 = blockIdx.y * 64;
  const int n0 = blockIdx.x * 128;
  const int koff = blockIdx.z * 1024;
  constexpr int ldK = 2048, NT = 16;

  constexpr int ACHUNK = 64 * 8;            // A: 64 rows * 8 chunks
  constexpr int TOT = 192 * 8;              // + B: 128 rows * 8 chunks
  __shared__ short sm[2][TOT * 8];

  f32x4 acc[2][4];
  #pragma unroll
  for (int a_ = 0; a_ < 2; ++a_)
    #pragma unroll
    for (int b_ = 0; b_ < 4; ++b_) acc[a_][b_] = f32x4{0.f, 0.f, 0.f, 0.f};

  auto stage = [&](int buf, int step) {
    const int kt = koff + (step << 6);
    #pragma unroll
    for (int i = 0; i < TOT / 256; ++i) {   // 6 loads/thread
      int p = i * 256 + tid;
      char* dst = (char*)(&sm[buf][0]) + p * 16;
      int row = p >> 3;
      int kcol = (p & 7) ^ (row & 7);
      const unsigned short* src;
      if (row < 64) src = A + (size_t)(m0 + row) * ldK + kt + kcol * 8;
      else          src = Bt + (size_t)(n0 + row - 64) * ldK + kt + kcol * 8;
      async16(src, dst);
    }
  };

  stage(0, 0);
  __syncthreads();

  int buf = 0;
  for (int step = 0; step < NT; ++step) {
    if (step + 1 < NT) stage(buf ^ 1, step + 1);
    const char* smA = (const char*)(&sm[buf][0]);
    const char* smB = smA + ACHUNK * 16;
    bf16x8 af[2][2], bfr[4][2];
    #pragma unroll
    for (int mf = 0; mf < 2; ++mf) {
      int row = wm * 32 + mf * 16 + lane15;
      #pragma unroll
      for (int kk = 0; kk < 2; ++kk) {
        int slot = (kk * 4 + kg) ^ (row & 7);
        af[mf][kk] = *(const bf16x8*)(smA + (row * 8 + slot) * 16);
      }
    }
    #pragma unroll
    for (int ff = 0; ff < 4; ++ff) {
      int row = wn * 64 + ff * 16 + lane15;
      #pragma unroll
      for (int kk = 0; kk < 2; ++kk) {
        int slot = (kk * 4 + kg) ^ (row & 7);
        bfr[ff][kk] = *(const bf16x8*)(smB + (row * 8 + slot) * 16);
      }
    }
    #pragma unroll
    for (int kk = 0; kk < 2; ++kk)
      #pragma unroll
      for (int mf = 0; mf < 2; ++mf)
        #pragma unroll
        for (int ff = 0; ff < 4; ++ff)
          acc[mf][ff] = __builtin_amdgcn_mfma_f32_16x16x32_bf16(
              af[mf][kk], bfr[ff][kk], acc[mf][ff], 0, 0, 0);
    __syncthreads();
    buf ^= 1;
  }

  float* out = Gp + (size_t)blockIdx.z * GPS;
  #pragma unroll
  for (int mf = 0; mf < 2; ++mf)
    #pragma unroll
    for (int ff = 0; ff < 4; ++ff) {
      int col = n0 + wn * 64 + ff * 16 + lane15;
      #pragma unroll
      for (int e = 0; e < 4; ++e) {
        int row = m0 + wm * 32 + mf * 16 + (lane >> 4) * 4 + e;
        out[(size_t)row * NPROJ + col] = acc[mf][ff][e];
      }
    }
}

// ---------------- K3: combine 4 j-blocks & 2 K-partials + chunk scan aggregates
__global__ __launch_bounds__(256) void k3_combine_scanA(
    const float* __restrict__ Gp, const float* __restrict__ bias64,
    float* __restrict__ a_arr, float* __restrict__ bd_arr,
    float* __restrict__ cm_arr, float* __restrict__ xcd_arr,
    float* __restrict__ aProd, float* __restrict__ hEnd)
{
  const int t = threadIdx.x;
  const int b = blockIdx.x >> 6, ch = blockIdx.x & 63;
  const int l0 = ch * CHUNK;
  __shared__ float comb[CHUNK][64];
  const size_t mbase = (size_t)b * 2048;

  for (int i = t; i < CHUNK * 64; i += 256) {
    int l = i >> 6, n = i & 63;
    float s = bias64[n];
    #pragma unroll
    for (int j = 0; j < 4; ++j) {
      int gl = l0 + l - 3 + j;
      if (gl >= 0) {
        size_t gi = (mbase + gl) * 256 + (j << 6) + n;
        s += Gp[gi] + Gp[gi + GPS];
      }
    }
    comb[l][n] = s;
  }
  __syncthreads();

  for (int i = t; i < CHUNK * 16; i += 256) {
    int l = i >> 4, n = i & 15;
    float d  = comb[l][n];
    float la = -0.5f * logf(1.0f + (float)(n + 1) * 0.0625f);
    float a  = __expf(d * la);
    float bd = d * comb[l][16 + n];
    size_t gi = ((mbase + l0 + l) << 4) + n;
    a_arr[gi] = a; bd_arr[gi] = bd; cm_arr[gi] = comb[l][32 + n];
    comb[l][n] = a; comb[l][16 + n] = bd;
  }
  if (t < CHUNK) xcd_arr[mbase + l0 + t] = comb[t][48];
  __syncthreads();

  if (t < 16) {
    float h = 0.f, p = 1.f;
    #pragma unroll 4
    for (int l = 0; l < CHUNK; ++l) {
      float a = comb[l][t], bd = comb[l][16 + t];
      p *= a; h = a * h + bd;
    }
    int idx = ((b * NCH + ch) << 4) + t;
    aProd[idx] = p; hEnd[idx] = h;
  }
}

// ---------------- K456: per-chunk prefix + scan + y*w_out broadcast ----------
__global__ __launch_bounds__(256) void k456_scan_out(
    const float* __restrict__ a_arr, const float* __restrict__ bd_arr,
    const float* __restrict__ cm_arr, const float* __restrict__ xcd_arr,
    const float* __restrict__ aProd, const float* __restrict__ hEnd,
    const float* __restrict__ w_out, float* __restrict__ out)
{
  const int t = threadIdx.x;
  const int b = blockIdx.x >> 6, ch = blockIdx.x & 63;
  const size_t base = (size_t)b * 2048 + ch * CHUNK;
  __shared__ float ylds[CHUNK];

  if (t < 16) {
    const int n = t;
    float h = 0.f;
    for (int p = 0; p < ch; ++p) {
      int idx = ((b * NCH + p) << 4) + n;
      h = aProd[idx] * h + hEnd[idx];
    }
    size_t gi = (base << 4) + n;
    float a0 = a_arr[gi], b0 = bd_arr[gi], c0 = cm_arr[gi];
    for (int l = 0; l < CHUNK; ++l) {
      float a1 = 0.f, b1 = 0.f, c1 = 0.f;
      if (l + 1 < CHUNK) {
        size_t gin = gi + 16;
        a1 = a_arr[gin]; b1 = bd_arr[gin]; c1 = cm_arr[gin];
      }
      h = a0 * h + b0;
      float p = c0 * h;
      p += __shfl_xor(p, 1); p += __shfl_xor(p, 2);
      p += __shfl_xor(p, 4); p += __shfl_xor(p, 8);
      if (n == 0) ylds[l] = p + xcd_arr[base + l];
      a0 = a1; b0 = b1; c0 = c1; gi += 16;
    }
  }
  __syncthreads();

  float4 w4 = *(const float4*)(w_out + t * 4);
  #pragma unroll 4
  for (int l = 0; l < CHUNK; ++l) {
    float yv = ylds[l];
    float4 o; o.x = yv * w4.x; o.y = yv * w4.y; o.z = yv * w4.z; o.w = yv * w4.w;
    *(float4*)(out + (base + l) * 1024 + t * 4) = o;
  }
}

extern "C" void kernel_launch(void* const* d_in, const int* in_sizes, int n_in,
                              void* d_out, int out_size, void* d_ws, size_t ws_size,
                              hipStream_t stream) {
  const float* x       = (const float*)d_in[0];
  const float* W_in    = (const float*)d_in[1];
  const float* conv_w  = (const float*)d_in[2];
  const float* conv_b  = (const float*)d_in[3];
  const float* W_delta = (const float*)d_in[4];
  const float* b_delta = (const float*)d_in[5];
  const float* W_B     = (const float*)d_in[6];
  const float* W_C     = (const float*)d_in[7];
  const float* Dv      = (const float*)d_in[8];
  const float* w_out   = (const float*)d_in[9];

  char* ws = (char*)d_ws;
  size_t off = 0;
  auto alloc = [&](size_t bytes) {
    size_t cur = off; off = (cur + bytes + 255) & ~(size_t)255; return ws + cur;
  };
  unsigned short* x_bf  = (unsigned short*)alloc((size_t)M * K1 * 2);      // 16.8MB
  unsigned short* Wt    = (unsigned short*)alloc((size_t)4096 * K1 * 2);   //  8.4MB
  unsigned short* WbigT = (unsigned short*)alloc((size_t)NPROJ * 2048 * 2);//  1.0MB
  float* bias64 = (float*)alloc(64 * 4);
  unsigned short* xg    = (unsigned short*)alloc((size_t)M * DI * 2);      // 33.6MB
  float* a_arr  = (float*)alloc((size_t)M * 16 * 4);
  float* bd_arr = (float*)alloc((size_t)M * 16 * 4);
  float* cm_arr = (float*)alloc((size_t)M * 16 * 4);
  float* xcd    = (float*)alloc((size_t)M * 4);
  float* aProd  = (float*)alloc(4 * NCH * 16 * 4);
  float* hEnd   = (float*)alloc(4 * NCH * 16 * 4);
  // Gp (2 x 8.4MB) aliases x_bf+Wt region: x_bf/Wt are dead after GEMM1.
  float* Gp = (float*)ws;

  k0_prep<<<7232, 256, 0, stream>>>(x, W_in, conv_w, conv_b, W_delta, b_delta,
                                    W_B, W_C, Dv, x_bf, Wt, WbigT, bias64);
  g1_gate<<<dim3(32, 64), 256, 0, stream>>>(x_bf, Wt, xg);
  gemm2_k<<<dim3(2, 128, 2), 256, 0, stream>>>(xg, WbigT, Gp);
  k3_combine_scanA<<<256, 256, 0, stream>>>(Gp, bias64, a_arr, bd_arr, cm_arr, xcd,
                                            aProd, hEnd);
  k456_scan_out<<<256, 256, 0, stream>>>(a_arr, bd_arr, cm_arr, xcd, aProd, hEnd,
                                         w_out, (float*)d_out);
}